// Round 8
// baseline (422.398 us; speedup 1.0000x reference)
//
#include <hip/hip_runtime.h>
#include <hip/hip_cooperative_groups.h>
#include <math.h>

namespace cg = cooperative_groups;

#define NB   1024
#define CH   60
#define SW   288
#define F1C  8
#define FD   16   // F1*D
#define F2C  16
#define KLEN 64
#define NCLS 4
#define NV   9
#define FEAT 144
#define NTHR 320
#define NREP 4    // class-sum replicas (atomic contention / 4)

#define XR_STRIDE 356
#define PH_STRIDE 76
#define W1_STRIDE 68

__device__ __forceinline__ float elu1(float v) {
    return v > 0.f ? v : __expf(v) - 1.f;   // native v_exp_f32
}

__device__ __forceinline__ unsigned short f2bf(float f) {   // RNE f32 -> bf16
    unsigned int u = __float_as_uint(f);
    u = (u + 0x7fffu + ((u >> 16) & 1u)) >> 16;
    return (unsigned short)u;
}

// ===== phase A: xr[b][f][w] = sum_ch dw[f][ch]*x[b][ch][w]; zero accumulators
__device__ __forceinline__ void phaseA(
    const float* __restrict__ x, const float* __restrict__ dw_w,
    unsigned short* __restrict__ xr, float* __restrict__ sums,
    int* __restrict__ cnt, float* __restrict__ cl, int nblk)
{
    const int tid = threadIdx.x, bid = blockIdx.x;
    if (bid == 0) {
        for (int i = tid; i < NREP * NCLS * FEAT; i += NTHR) sums[i] = 0.f;
        if (tid < NREP * NCLS) cnt[tid] = 0;
        if (tid == 0) cl[0] = 0.f;
    }
    for (int g = bid * NTHR + tid; g < NB * SW; g += nblk * NTHR) {
        const int b = g / SW;              // const-divisor magic mul
        const int w = g - b * SW;
        const float* xp = x + (size_t)b * (CH * SW) + w;
        float acc[FD];
        #pragma unroll
        for (int f = 0; f < FD; ++f) acc[f] = 0.f;
        float v[30];
        #pragma unroll
        for (int j = 0; j < 30; ++j) v[j] = xp[j * SW];     // 30 loads in flight
        #pragma unroll
        for (int j = 0; j < 30; ++j) {
            const float xv = v[j];
            #pragma unroll
            for (int f = 0; f < FD; ++f)
                acc[f] = fmaf(dw_w[f * CH + j], xv, acc[f]);        // s_load
        }
        #pragma unroll
        for (int j = 0; j < 30; ++j) v[j] = xp[(30 + j) * SW];
        #pragma unroll
        for (int j = 0; j < 30; ++j) {
            const float xv = v[j];
            #pragma unroll
            for (int f = 0; f < FD; ++f)
                acc[f] = fmaf(dw_w[f * CH + 30 + j], xv, acc[f]);
        }
        const size_t base = (size_t)b * (FD * SW) + w;
        #pragma unroll
        for (int f = 0; f < FD; ++f) xr[base + f * SW] = f2bf(acc[f]);
    }
}

// ===== phase B: per-sample conv(K=64)+bn2+elu+pool4 + pointwise+bn3+elu+pool8
//       + feat store + class-sum atomics + softmax
__device__ __forceinline__ void phaseB(
    const unsigned short* __restrict__ xr, const int* __restrict__ y,
    const float* __restrict__ conv1_w, const float* __restrict__ dw_w,
    const float* __restrict__ bn1_g, const float* __restrict__ bn1_b,
    const float* __restrict__ bn1_m, const float* __restrict__ bn1_v,
    const float* __restrict__ bn2_g, const float* __restrict__ bn2_b,
    const float* __restrict__ bn2_m, const float* __restrict__ bn2_v,
    const float* __restrict__ pw_w,
    const float* __restrict__ bn3_g, const float* __restrict__ bn3_b,
    const float* __restrict__ bn3_m, const float* __restrict__ bn3_v,
    const float* __restrict__ fc_w, const float* __restrict__ fc_b,
    float* __restrict__ probs_out, float* __restrict__ feat_out,
    float* __restrict__ sums, int* __restrict__ cnt, int nblk)
{
    __shared__ __align__(16) float s_xr[FD * XR_STRIDE];
    __shared__ __align__(16) float s_w1[F1C * W1_STRIDE];
    __shared__ __align__(16) float s_ph[FD * PH_STRIDE];
    __shared__ float s_pwT[FD * F2C];
    __shared__ float s_feat[FEAT];
    __shared__ float s_A[FD], s_Cb[FD], s_a3[F2C], s_c3[F2C];
    const int tid = threadIdx.x;

    // one-time, sample-invariant staging
    for (int i = tid; i < F1C * KLEN; i += NTHR)
        s_w1[(i >> 6) * W1_STRIDE + (i & 63)] = conv1_w[i];
    for (int i = tid; i < F2C * FD; i += NTHR)
        s_pwT[(i & 15) * F2C + (i >> 4)] = pw_w[i];
    for (int i = tid; i < FD * 68; i += NTHR) {   // pads [0,32) & [320,356)
        int f = i / 68, p = i % 68;
        int wp = (p < 32) ? p : (288 + p);
        s_xr[f * XR_STRIDE + wp] = 0.f;
    }
    if (tid < FD) {
        const int f = tid, f1 = f >> 1;
        const float inv1 = bn1_g[f1] / sqrtf(bn1_v[f1] + 1e-3f);
        const float c1 = bn1_b[f1] - bn1_m[f1] * inv1;
        const float inv2 = bn2_g[f] / sqrtf(bn2_v[f] + 1e-3f);
        const float c2 = bn2_b[f] - bn2_m[f] * inv2;
        float sdw = 0.f;
        for (int ch = 0; ch < CH; ++ch) sdw += dw_w[f * CH + ch];
        s_A[f] = inv2 * inv1;
        s_Cb[f] = inv2 * c1 * sdw + c2;
        const float inv3 = bn3_g[f] / sqrtf(bn3_v[f] + 1e-3f);
        s_a3[f] = inv3;
        s_c3[f] = bn3_b[f] - bn3_m[f] * inv3;
    }

    for (int b = blockIdx.x; b < NB; b += nblk) {
        __syncthreads();                       // covers staging + s_xr reuse
        {
            const uint4* xrb = (const uint4*)(xr + (size_t)b * (FD * SW));
            for (int i = tid; i < 576; i += NTHR) {
                const int f = i / 36;
                const int k = i - f * 36;
                const uint4 v = xrb[i];
                float* dst = &s_xr[f * XR_STRIDE + 32 + 8 * k];
                float4 lo, hi;
                lo.x = __uint_as_float(v.x << 16); lo.y = __uint_as_float(v.x & 0xffff0000u);
                lo.z = __uint_as_float(v.y << 16); lo.w = __uint_as_float(v.y & 0xffff0000u);
                hi.x = __uint_as_float(v.z << 16); hi.y = __uint_as_float(v.z & 0xffff0000u);
                hi.z = __uint_as_float(v.w << 16); hi.w = __uint_as_float(v.w & 0xffff0000u);
                *(float4*)dst = lo;
                *(float4*)(dst + 4) = hi;
            }
        }
        __syncthreads();

        if (tid < 288) {                       // conv + bn2 + elu + pool4
            const int f = tid & 15;
            const int q = tid >> 4;            // 0..17
            const float4* xp = (const float4*)&s_xr[f * XR_STRIDE + 16 * q];
            const float4* wp = (const float4*)&s_w1[(f >> 1) * W1_STRIDE];
            float cw[20];
            #pragma unroll
            for (int i = 0; i < 4; ++i) {
                const float4 t = xp[i];
                cw[4*i] = t.x; cw[4*i+1] = t.y; cw[4*i+2] = t.z; cw[4*i+3] = t.w;
            }
            float bb[16];
            #pragma unroll
            for (int j = 0; j < 16; ++j) bb[j] = 0.f;
            #pragma unroll
            for (int m = 0; m < 16; ++m) {
                {
                    const float4 t = xp[m + 4];
                    const int s = (4 * (m + 4)) % 20;
                    cw[s] = t.x; cw[s+1] = t.y; cw[s+2] = t.z; cw[s+3] = t.w;
                }
                const float4 wv = wp[m];
                #pragma unroll
                for (int j = 0; j < 16; ++j) {
                    bb[j] = fmaf(wv.x, cw[(4*m + j    ) % 20], bb[j]);
                    bb[j] = fmaf(wv.y, cw[(4*m + j + 1) % 20], bb[j]);
                    bb[j] = fmaf(wv.z, cw[(4*m + j + 2) % 20], bb[j]);
                    bb[j] = fmaf(wv.w, cw[(4*m + j + 3) % 20], bb[j]);
                }
            }
            const float Af = s_A[f], Cf = s_Cb[f];
            float e[16];
            #pragma unroll
            for (int j = 0; j < 16; ++j) e[j] = elu1(fmaf(Af, bb[j], Cf));
            float4 ph;
            ph.x = (e[0]  + e[1]  + e[2]  + e[3])  * 0.25f;
            ph.y = (e[4]  + e[5]  + e[6]  + e[7])  * 0.25f;
            ph.z = (e[8]  + e[9]  + e[10] + e[11]) * 0.25f;
            ph.w = (e[12] + e[13] + e[14] + e[15]) * 0.25f;
            *(float4*)&s_ph[f * PH_STRIDE + 4 * q] = ph;
        }
        __syncthreads();

        if (tid < FEAT) {                      // pointwise + bn3 + elu + pool8
            const int f2 = tid / NV;
            const int v = tid - f2 * NV;
            float su[8];
            #pragma unroll
            for (int k = 0; k < 8; ++k) su[k] = 0.f;
            #pragma unroll
            for (int f = 0; f < FD; ++f) {
                const float w = s_pwT[f * F2C + f2];
                const float4 p0 = *(const float4*)&s_ph[f * PH_STRIDE + 8 * v];
                const float4 p1 = *(const float4*)&s_ph[f * PH_STRIDE + 8 * v + 4];
                su[0] = fmaf(w, p0.x, su[0]); su[1] = fmaf(w, p0.y, su[1]);
                su[2] = fmaf(w, p0.z, su[2]); su[3] = fmaf(w, p0.w, su[3]);
                su[4] = fmaf(w, p1.x, su[4]); su[5] = fmaf(w, p1.y, su[5]);
                su[6] = fmaf(w, p1.z, su[6]); su[7] = fmaf(w, p1.w, su[7]);
            }
            const float a3f = s_a3[f2], c3f = s_c3[f2];
            float acc = 0.f;
            #pragma unroll
            for (int k = 0; k < 8; ++k) acc += elu1(fmaf(a3f, su[k], c3f));
            const float ft = acc * 0.125f;
            s_feat[tid] = ft;
            feat_out[(size_t)b * FEAT + tid] = ft;
            atomicAdd(&sums[((b & (NREP - 1)) * NCLS + y[b]) * FEAT + tid], ft);
        }
        if (tid == 0) atomicAdd(&cnt[(b & (NREP - 1)) * NCLS + y[b]], 1);
        __syncthreads();

        if (tid < 64) {                        // logits + softmax (wave 0)
            float lg0 = 0.f, lg1 = 0.f, lg2 = 0.f, lg3 = 0.f;
            for (int j = tid; j < FEAT; j += 64) {
                const float fv = s_feat[j];
                lg0 = fmaf(fv, fc_w[0 * FEAT + j], lg0);
                lg1 = fmaf(fv, fc_w[1 * FEAT + j], lg1);
                lg2 = fmaf(fv, fc_w[2 * FEAT + j], lg2);
                lg3 = fmaf(fv, fc_w[3 * FEAT + j], lg3);
            }
            #pragma unroll
            for (int off = 32; off > 0; off >>= 1) {
                lg0 += __shfl_down(lg0, off, 64);
                lg1 += __shfl_down(lg1, off, 64);
                lg2 += __shfl_down(lg2, off, 64);
                lg3 += __shfl_down(lg3, off, 64);
            }
            if (tid == 0) {
                lg0 += fc_b[0]; lg1 += fc_b[1]; lg2 += fc_b[2]; lg3 += fc_b[3];
                const float m = fmaxf(fmaxf(lg0, lg1), fmaxf(lg2, lg3));
                const float e0 = __expf(lg0 - m), e1 = __expf(lg1 - m);
                const float e2 = __expf(lg2 - m), e3 = __expf(lg3 - m);
                const float inv = 1.f / (e0 + e1 + e2 + e3);
                float* po = probs_out + (size_t)b * NCLS;
                po[0] = e0 * inv; po[1] = e1 * inv; po[2] = e2 * inv; po[3] = e3 * inv;
            }
        }
    }
}

// ===== phase C: centroid distance per sample, atomic mean into cl ===========
__device__ __forceinline__ void phaseC(
    const float* __restrict__ feat, const int* __restrict__ y,
    const float* __restrict__ sums, const int* __restrict__ cnt,
    float* __restrict__ cl, int nblk)
{
    __shared__ float s_redc[8];
    const int tid = threadIdx.x;
    for (int b = blockIdx.x; b < NB; b += nblk) {
        const int c = y[b];
        float part = 0.f;
        if (tid < FEAT) {
            const float sm = sums[(0 * NCLS + c) * FEAT + tid]
                           + sums[(1 * NCLS + c) * FEAT + tid]
                           + sums[(2 * NCLS + c) * FEAT + tid]
                           + sums[(3 * NCLS + c) * FEAT + tid];
            const float cf = (float)(cnt[0 * NCLS + c] + cnt[1 * NCLS + c]
                                   + cnt[2 * NCLS + c] + cnt[3 * NCLS + c]);
            const float cent = sm / fmaxf(cf, 1.0f);
            const float d = feat[(size_t)b * FEAT + tid] - cent + 1e-6f;
            part = d * d;
        }
        #pragma unroll
        for (int off = 32; off > 0; off >>= 1) part += __shfl_down(part, off, 64);
        if ((tid & 63) == 0) s_redc[tid >> 6] = part;
        __syncthreads();
        if (tid == 0)
            atomicAdd(cl, sqrtf(s_redc[0] + s_redc[1] + s_redc[2] + s_redc[3]
                                + s_redc[4]) * (1.0f / 1024.0f));
        __syncthreads();
    }
}

// ===== cooperative fused kernel =============================================
__global__ __launch_bounds__(NTHR, 5) void eegnet_coop(
    const float* x, const int* y, const float* conv1_w,
    const float* bn1_g, const float* bn1_b, const float* bn1_m, const float* bn1_v,
    const float* dw_w,
    const float* bn2_g, const float* bn2_b, const float* bn2_m, const float* bn2_v,
    const float* pw_w,
    const float* bn3_g, const float* bn3_b, const float* bn3_m, const float* bn3_v,
    const float* fc_w, const float* fc_b,
    float* probs, float* feat, float* sums, int* cnt,
    unsigned short* xr, float* cl)
{
    cg::grid_group grid = cg::this_grid();
    const int nblk = gridDim.x;
    phaseA(x, dw_w, xr, sums, cnt, cl, nblk);
    __threadfence();
    grid.sync();
    __threadfence();
    phaseB(xr, y, conv1_w, dw_w, bn1_g, bn1_b, bn1_m, bn1_v,
           bn2_g, bn2_b, bn2_m, bn2_v, pw_w, bn3_g, bn3_b, bn3_m, bn3_v,
           fc_w, fc_b, probs, feat, sums, cnt, nblk);
    __threadfence();
    grid.sync();
    __threadfence();
    phaseC(feat, y, sums, cnt, cl, nblk);
}

// ===== fallback: same phases as ordinary kernels ============================
__global__ __launch_bounds__(NTHR, 5) void eegnet_kA(
    const float* x, const float* dw_w, unsigned short* xr,
    float* sums, int* cnt, float* cl)
{ phaseA(x, dw_w, xr, sums, cnt, cl, gridDim.x); }

__global__ __launch_bounds__(NTHR, 5) void eegnet_kB(
    const unsigned short* xr, const int* y, const float* conv1_w, const float* dw_w,
    const float* bn1_g, const float* bn1_b, const float* bn1_m, const float* bn1_v,
    const float* bn2_g, const float* bn2_b, const float* bn2_m, const float* bn2_v,
    const float* pw_w,
    const float* bn3_g, const float* bn3_b, const float* bn3_m, const float* bn3_v,
    const float* fc_w, const float* fc_b,
    float* probs, float* feat, float* sums, int* cnt)
{ phaseB(xr, y, conv1_w, dw_w, bn1_g, bn1_b, bn1_m, bn1_v,
         bn2_g, bn2_b, bn2_m, bn2_v, pw_w, bn3_g, bn3_b, bn3_m, bn3_v,
         fc_w, fc_b, probs, feat, sums, cnt, gridDim.x); }

__global__ __launch_bounds__(NTHR, 5) void eegnet_kC(
    const float* feat, const int* y, const float* sums, const int* cnt, float* cl)
{ phaseC(feat, y, sums, cnt, cl, gridDim.x); }

extern "C" void kernel_launch(void* const* d_in, const int* in_sizes, int n_in,
                              void* d_out, int out_size, void* d_ws, size_t ws_size,
                              hipStream_t stream) {
    const float* x       = (const float*)d_in[0];
    const int*   y       = (const int*)d_in[1];
    const float* conv1_w = (const float*)d_in[2];
    const float* bn1_g   = (const float*)d_in[3];
    const float* bn1_b   = (const float*)d_in[4];
    const float* bn1_m   = (const float*)d_in[5];
    const float* bn1_v   = (const float*)d_in[6];
    const float* dw_w    = (const float*)d_in[7];
    const float* bn2_g   = (const float*)d_in[8];
    const float* bn2_b   = (const float*)d_in[9];
    const float* bn2_m   = (const float*)d_in[10];
    const float* bn2_v   = (const float*)d_in[11];
    const float* pw_w    = (const float*)d_in[12];
    const float* bn3_g   = (const float*)d_in[13];
    const float* bn3_b   = (const float*)d_in[14];
    const float* bn3_m   = (const float*)d_in[15];
    const float* bn3_v   = (const float*)d_in[16];
    const float* fc_w    = (const float*)d_in[17];
    const float* fc_b    = (const float*)d_in[18];

    float* out   = (float*)d_out;
    float* probs = out;                               // [1024*4]
    float* cl    = out + 4096;                        // [1]
    char*  ws    = (char*)d_ws;
    float* sums  = (float*)ws;                        // [4][4][144] = 9216 B
    int*   cnt   = (int*)(ws + 9216);                 // [4][4] = 64 B
    float* feat  = (float*)(ws + 9280);               // 1024*144 f32 (16B-aligned)
    unsigned short* xr = (unsigned short*)(ws + 9280 + 589824);  // bf16, 9.44 MB

    int maxPerCU = 0;
    hipError_t oe = hipOccupancyMaxActiveBlocksPerMultiprocessor(
        &maxPerCU, eegnet_coop, NTHR, 0);
    if (oe == hipSuccess && maxPerCU > 0) {
        int grid = maxPerCU * 256;
        if (grid > NB) grid = NB;
        void* args[] = {
            (void*)&x, (void*)&y, (void*)&conv1_w,
            (void*)&bn1_g, (void*)&bn1_b, (void*)&bn1_m, (void*)&bn1_v,
            (void*)&dw_w,
            (void*)&bn2_g, (void*)&bn2_b, (void*)&bn2_m, (void*)&bn2_v,
            (void*)&pw_w,
            (void*)&bn3_g, (void*)&bn3_b, (void*)&bn3_m, (void*)&bn3_v,
            (void*)&fc_w, (void*)&fc_b,
            (void*)&probs, (void*)&feat, (void*)&sums, (void*)&cnt,
            (void*)&xr, (void*)&cl
        };
        hipError_t le = hipLaunchCooperativeKernel(
            (const void*)eegnet_coop, dim3(grid), dim3(NTHR), args, 0, stream);
        if (le == hipSuccess) return;
    }

    // fallback: ordinary 3-kernel pipeline (kernel boundaries = implicit sync)
    eegnet_kA<<<NB, NTHR, 0, stream>>>(x, dw_w, xr, sums, cnt, cl);
    eegnet_kB<<<NB, NTHR, 0, stream>>>(
        xr, y, conv1_w, dw_w, bn1_g, bn1_b, bn1_m, bn1_v,
        bn2_g, bn2_b, bn2_m, bn2_v, pw_w, bn3_g, bn3_b, bn3_m, bn3_v,
        fc_w, fc_b, probs, feat, sums, cnt);
    eegnet_kC<<<NB, NTHR, 0, stream>>>(feat, y, sums, cnt, cl);
}

// Round 9
// 55.040 us; speedup vs baseline: 7.6744x; 7.6744x over previous
//
#include <hip/hip_runtime.h>
#include <math.h>

#define NB   1024
#define CH   60
#define SW   288
#define F1C  8
#define FD   16   // F1*D
#define F2C  16
#define KLEN 64
#define NCLS 4
#define NV   9
#define FEAT 144
#define NTHR 320
#define NREP 4    // class-sum replicas (atomic contention / 4)

#define XR_STRIDE 356   // mult of 4 (b128-aligned rows)
#define PH_STRIDE 76
#define W1_STRIDE 68

__device__ __forceinline__ float elu1(float v) {
    return v > 0.f ? v : __expf(v) - 1.f;   // native v_exp_f32
}

// ===== fused per-sample forward: chreduce -> conv -> pointwise -> softmax ===
// block b = sample b. 1024 blocks x 320 threads, 4 blocks/CU (one pass).
// chreduce uses the R5-A proven pattern (30-deep reg burst + s_load weights)
// but writes f32 straight to LDS -- no xr global round-trip.
__global__ __launch_bounds__(NTHR, 5) void eegnet_fwd(
    const float* __restrict__ x, const int* __restrict__ y,
    const float* __restrict__ conv1_w,
    const float* __restrict__ bn1_g, const float* __restrict__ bn1_b,
    const float* __restrict__ bn1_m, const float* __restrict__ bn1_v,
    const float* __restrict__ dw_w,
    const float* __restrict__ bn2_g, const float* __restrict__ bn2_b,
    const float* __restrict__ bn2_m, const float* __restrict__ bn2_v,
    const float* __restrict__ pw_w,
    const float* __restrict__ bn3_g, const float* __restrict__ bn3_b,
    const float* __restrict__ bn3_m, const float* __restrict__ bn3_v,
    const float* __restrict__ fc_w, const float* __restrict__ fc_b,
    float* __restrict__ probs_out, float* __restrict__ feat_out,
    float* __restrict__ sums, int* __restrict__ cnt)
{
    __shared__ __align__(16) float s_xr[FD * XR_STRIDE];
    __shared__ __align__(16) float s_w1[F1C * W1_STRIDE];
    __shared__ __align__(16) float s_ph[FD * PH_STRIDE];
    __shared__ float s_pwT[FD * F2C];
    __shared__ float s_feat[FEAT];
    __shared__ float s_A[FD], s_Cb[FD], s_a3[F2C], s_c3[F2C];

    const int tid = threadIdx.x;
    const int b = blockIdx.x;

    // ---- stage weights, zero xr pads, BN folds (no barrier needed yet) ----
    if (tid == 0) atomicAdd(&cnt[(b & (NREP - 1)) * NCLS + y[b]], 1);
    for (int i = tid; i < F1C * KLEN; i += NTHR)
        s_w1[(i >> 6) * W1_STRIDE + (i & 63)] = conv1_w[i];
    for (int i = tid; i < F2C * FD; i += NTHR)
        s_pwT[(i & 15) * F2C + (i >> 4)] = pw_w[i];
    for (int i = tid; i < FD * 68; i += NTHR) {     // pads [0,32) & [320,356)
        int f = i / 68, p = i % 68;
        int wp = (p < 32) ? p : (288 + p);
        s_xr[f * XR_STRIDE + wp] = 0.f;
    }
    if (tid < FD) {
        const int f = tid, f1 = f >> 1;
        const float inv1 = bn1_g[f1] / sqrtf(bn1_v[f1] + 1e-3f);
        const float c1 = bn1_b[f1] - bn1_m[f1] * inv1;
        const float inv2 = bn2_g[f] / sqrtf(bn2_v[f] + 1e-3f);
        const float c2 = bn2_b[f] - bn2_m[f] * inv2;
        float sdw = 0.f;
        for (int ch = 0; ch < CH; ++ch) sdw += dw_w[f * CH + ch];
        s_A[f] = inv2 * inv1;
        s_Cb[f] = inv2 * c1 * sdw + c2;
        const float inv3 = bn3_g[f] / sqrtf(bn3_v[f] + 1e-3f);
        s_a3[f] = inv3;
        s_c3[f] = bn3_b[f] - bn3_m[f] * inv3;
    }

    // ---- phase 1: xr[f][w] = sum_ch dw[f][ch]*x[b][ch][w] (f32, in LDS) ----
    if (tid < SW) {
        const float* xp = x + (size_t)b * (CH * SW) + tid;
        float acc[FD];
        #pragma unroll
        for (int f = 0; f < FD; ++f) acc[f] = 0.f;
        float v[30];
        #pragma unroll
        for (int j = 0; j < 30; ++j) v[j] = xp[j * SW];     // 30 loads in flight
        #pragma unroll
        for (int j = 0; j < 30; ++j) {
            const float xv = v[j];
            #pragma unroll
            for (int f = 0; f < FD; ++f)
                acc[f] = fmaf(dw_w[f * CH + j], xv, acc[f]);        // s_load
        }
        #pragma unroll
        for (int j = 0; j < 30; ++j) v[j] = xp[(30 + j) * SW];  // batch 2
        #pragma unroll
        for (int j = 0; j < 30; ++j) {
            const float xv = v[j];
            #pragma unroll
            for (int f = 0; f < FD; ++f)
                acc[f] = fmaf(dw_w[f * CH + 30 + j], xv, acc[f]);
        }
        #pragma unroll
        for (int f = 0; f < FD; ++f) s_xr[f * XR_STRIDE + 32 + tid] = acc[f];
    }
    __syncthreads();

    // ---- phase 2: K=64 conv + bn2 + elu + pool4 (16 conv outputs/thread) ----
    if (tid < 288) {
        const int f = tid & 15;
        const int q = tid >> 4;                   // 0..17
        const float4* xp = (const float4*)&s_xr[f * XR_STRIDE + 16 * q];
        const float4* wp = (const float4*)&s_w1[(f >> 1) * W1_STRIDE];
        float cw[20];
        #pragma unroll
        for (int i = 0; i < 4; ++i) {
            const float4 t = xp[i];
            cw[4*i] = t.x; cw[4*i+1] = t.y; cw[4*i+2] = t.z; cw[4*i+3] = t.w;
        }
        float bb[16];
        #pragma unroll
        for (int j = 0; j < 16; ++j) bb[j] = 0.f;
        #pragma unroll
        for (int m = 0; m < 16; ++m) {
            {
                const float4 t = xp[m + 4];
                const int s = (4 * (m + 4)) % 20;   // mult of 4, no mid-vec wrap
                cw[s] = t.x; cw[s+1] = t.y; cw[s+2] = t.z; cw[s+3] = t.w;
            }
            const float4 wv = wp[m];
            #pragma unroll
            for (int j = 0; j < 16; ++j) {
                bb[j] = fmaf(wv.x, cw[(4*m + j    ) % 20], bb[j]);
                bb[j] = fmaf(wv.y, cw[(4*m + j + 1) % 20], bb[j]);
                bb[j] = fmaf(wv.z, cw[(4*m + j + 2) % 20], bb[j]);
                bb[j] = fmaf(wv.w, cw[(4*m + j + 3) % 20], bb[j]);
            }
        }
        const float Af = s_A[f], Cf = s_Cb[f];
        float e[16];
        #pragma unroll
        for (int j = 0; j < 16; ++j) e[j] = elu1(fmaf(Af, bb[j], Cf));
        float4 ph;
        ph.x = (e[0]  + e[1]  + e[2]  + e[3])  * 0.25f;
        ph.y = (e[4]  + e[5]  + e[6]  + e[7])  * 0.25f;
        ph.z = (e[8]  + e[9]  + e[10] + e[11]) * 0.25f;
        ph.w = (e[12] + e[13] + e[14] + e[15]) * 0.25f;
        *(float4*)&s_ph[f * PH_STRIDE + 4 * q] = ph;
    }
    __syncthreads();

    // ---- phase 3: pointwise 16x16 + bn3 + elu + pool8 -> feat[144] ----
    if (tid < FEAT) {
        const int f2 = tid / NV;
        const int v = tid - f2 * NV;
        float su[8];
        #pragma unroll
        for (int k = 0; k < 8; ++k) su[k] = 0.f;
        #pragma unroll
        for (int f = 0; f < FD; ++f) {
            const float w = s_pwT[f * F2C + f2];
            const float4 p0 = *(const float4*)&s_ph[f * PH_STRIDE + 8 * v];
            const float4 p1 = *(const float4*)&s_ph[f * PH_STRIDE + 8 * v + 4];
            su[0] = fmaf(w, p0.x, su[0]); su[1] = fmaf(w, p0.y, su[1]);
            su[2] = fmaf(w, p0.z, su[2]); su[3] = fmaf(w, p0.w, su[3]);
            su[4] = fmaf(w, p1.x, su[4]); su[5] = fmaf(w, p1.y, su[5]);
            su[6] = fmaf(w, p1.z, su[6]); su[7] = fmaf(w, p1.w, su[7]);
        }
        const float a3f = s_a3[f2], c3f = s_c3[f2];
        float acc = 0.f;
        #pragma unroll
        for (int k = 0; k < 8; ++k) acc += elu1(fmaf(a3f, su[k], c3f));
        const float ft = acc * 0.125f;
        s_feat[tid] = ft;
        feat_out[(size_t)b * FEAT + tid] = ft;
        atomicAdd(&sums[((b & (NREP - 1)) * NCLS + y[b]) * FEAT + tid], ft);
    }
    __syncthreads();

    // ---- phase 4: logits + softmax (wave 0; fc_w from L2) ----
    if (tid < 64) {
        float lg0 = 0.f, lg1 = 0.f, lg2 = 0.f, lg3 = 0.f;
        for (int j = tid; j < FEAT; j += 64) {
            const float fv = s_feat[j];
            lg0 = fmaf(fv, fc_w[0 * FEAT + j], lg0);
            lg1 = fmaf(fv, fc_w[1 * FEAT + j], lg1);
            lg2 = fmaf(fv, fc_w[2 * FEAT + j], lg2);
            lg3 = fmaf(fv, fc_w[3 * FEAT + j], lg3);
        }
        #pragma unroll
        for (int off = 32; off > 0; off >>= 1) {
            lg0 += __shfl_down(lg0, off, 64);
            lg1 += __shfl_down(lg1, off, 64);
            lg2 += __shfl_down(lg2, off, 64);
            lg3 += __shfl_down(lg3, off, 64);
        }
        if (tid == 0) {
            lg0 += fc_b[0]; lg1 += fc_b[1]; lg2 += fc_b[2]; lg3 += fc_b[3];
            const float m = fmaxf(fmaxf(lg0, lg1), fmaxf(lg2, lg3));
            const float e0 = __expf(lg0 - m), e1 = __expf(lg1 - m);
            const float e2 = __expf(lg2 - m), e3 = __expf(lg3 - m);
            const float inv = 1.f / (e0 + e1 + e2 + e3);
            float* po = probs_out + (size_t)b * NCLS;
            po[0] = e0 * inv; po[1] = e1 * inv; po[2] = e2 * inv; po[3] = e3 * inv;
        }
    }
}

// ===== centroid distances (reads replicated sums + cnt) =====================
__global__ __launch_bounds__(64) void eegnet_dist(
    const float* __restrict__ feat, const int* __restrict__ y,
    const float* __restrict__ sums, const int* __restrict__ cnt,
    float* __restrict__ cl_out)
{
    __shared__ float s_cent[NCLS * FEAT];
    const int tid = threadIdx.x;
    for (int i = tid; i < NCLS * FEAT; i += 64) {
        const int c = i / FEAT;
        const float sm = sums[(0 * NCLS + c) * FEAT + (i - c * FEAT)]
                       + sums[(1 * NCLS + c) * FEAT + (i - c * FEAT)]
                       + sums[(2 * NCLS + c) * FEAT + (i - c * FEAT)]
                       + sums[(3 * NCLS + c) * FEAT + (i - c * FEAT)];
        const float cf = (float)(cnt[0 * NCLS + c] + cnt[1 * NCLS + c]
                               + cnt[2 * NCLS + c] + cnt[3 * NCLS + c]);
        s_cent[i] = sm / fmaxf(cf, 1.0f);
    }
    __syncthreads();

    const int s = blockIdx.x * 64 + tid;
    const float* fp = feat + (size_t)s * FEAT;
    const float* cp = &s_cent[y[s] * FEAT];
    float acc = 0.f;
    #pragma unroll
    for (int j = 0; j < FEAT; j += 4) {
        const float4 fv = *reinterpret_cast<const float4*>(fp + j);
        float d;
        d = fv.x - cp[j + 0] + 1e-6f; acc = fmaf(d, d, acc);
        d = fv.y - cp[j + 1] + 1e-6f; acc = fmaf(d, d, acc);
        d = fv.z - cp[j + 2] + 1e-6f; acc = fmaf(d, d, acc);
        d = fv.w - cp[j + 3] + 1e-6f; acc = fmaf(d, d, acc);
    }
    float dist = sqrtf(acc);
    #pragma unroll
    for (int off = 32; off > 0; off >>= 1) dist += __shfl_down(dist, off, 64);
    if (tid == 0) atomicAdd(cl_out, dist * (1.0f / 1024.0f));
}

extern "C" void kernel_launch(void* const* d_in, const int* in_sizes, int n_in,
                              void* d_out, int out_size, void* d_ws, size_t ws_size,
                              hipStream_t stream) {
    const float* x       = (const float*)d_in[0];
    const int*   y       = (const int*)d_in[1];
    const float* conv1_w = (const float*)d_in[2];
    const float* bn1_g   = (const float*)d_in[3];
    const float* bn1_b   = (const float*)d_in[4];
    const float* bn1_m   = (const float*)d_in[5];
    const float* bn1_v   = (const float*)d_in[6];
    const float* dw_w    = (const float*)d_in[7];
    const float* bn2_g   = (const float*)d_in[8];
    const float* bn2_b   = (const float*)d_in[9];
    const float* bn2_m   = (const float*)d_in[10];
    const float* bn2_v   = (const float*)d_in[11];
    const float* pw_w    = (const float*)d_in[12];
    const float* bn3_g   = (const float*)d_in[13];
    const float* bn3_b   = (const float*)d_in[14];
    const float* bn3_m   = (const float*)d_in[15];
    const float* bn3_v   = (const float*)d_in[16];
    const float* fc_w    = (const float*)d_in[17];
    const float* fc_b    = (const float*)d_in[18];

    float* out   = (float*)d_out;
    float* probs = out;                               // [1024*4]
    float* cl    = out + 4096;                        // [1]
    char*  ws    = (char*)d_ws;
    float* sums  = (float*)ws;                        // [4][4][144] = 9216 B
    int*   cnt   = (int*)(ws + 9216);                 // [4][4] = 64 B
    float* feat  = (float*)(ws + 9280);               // 1024*144 f32, 16B-aligned

    hipMemsetAsync(ws, 0, 9280, stream);              // sums + cnt
    hipMemsetAsync(cl, 0, sizeof(float), stream);     // loss accumulator
    eegnet_fwd<<<NB, NTHR, 0, stream>>>(
        x, y, conv1_w, bn1_g, bn1_b, bn1_m, bn1_v,
        dw_w, bn2_g, bn2_b, bn2_m, bn2_v,
        pw_w, bn3_g, bn3_b, bn3_m, bn3_v,
        fc_w, fc_b, probs, feat, sums, cnt);
    eegnet_dist<<<16, 64, 0, stream>>>(feat, y, sums, cnt, cl);
}